// Round 1
// 581.567 us; speedup vs baseline: 1.5207x; 1.5207x over previous
//
#include <hip/hip_runtime.h>

#define LN_EPS 1e-5f

typedef __attribute__((ext_vector_type(8))) short bf16x8;   // 8 bf16 = 4 VGPRs
typedef __attribute__((ext_vector_type(4))) float f32x4;    // 4 fp32 acc

__device__ __forceinline__ unsigned short f2bf(float f) {
    unsigned int u = __float_as_uint(f);
    u += 0x7fffu + ((u >> 16) & 1u);   // RNE
    return (unsigned short)(u >> 16);
}
__device__ __forceinline__ unsigned int cvt_pk_bf16(float lo, float hi) {
    unsigned int r;
    asm("v_cvt_pk_bf16_f32 %0, %1, %2" : "=v"(r) : "v"(lo), "v"(hi));
    return r;
}

// N=65536, D=256, Hd=1024, E=8
#define DD   256
#define HD   1024
#define NE   8
#define TN   64      // nodes per block
#define LDH  264     // LDS row stride (bf16 elems): +8 pad -> balanced b128 groups
#define GWS  260     // sGW row stride (floats): +4 pad -> conflict-free float4 reads

// ---------------- weight packing: exact per-lane consumption order ----------------
// Layout: frag index t_global = ((((e*4 + c)*4 + w)*32 + (kk*4+im))*64 + lane), 8 bf16 each.
// Stage1 frag (kk,im), lane(l15,qd): W1[e][d = kk*32+qd*8+j][h = c*256+w*64+im*16+l15]
__global__ void pack_w1(const float* __restrict__ W1, unsigned short* __restrict__ pw1) {
    int t = blockIdx.x * 256 + threadIdx.x;     // 0..262143
    int lane = t & 63;
    int l15 = lane & 15, qd = lane >> 4;
    int tt = (t >> 6) & 31;
    int im = tt & 3, kk = tt >> 2;
    int w = (t >> 11) & 3;
    int c = (t >> 13) & 3;
    int e = t >> 15;
    int d0 = kk * 32 + qd * 8;
    int h  = c * 256 + w * 64 + im * 16 + l15;
    const float* src = W1 + ((size_t)(e * 256 + d0)) * 1024 + h;
    union { unsigned short s[8]; int4 v; } u;
#pragma unroll
    for (int j = 0; j < 8; ++j) u.s[j] = f2bf(src[(size_t)j * 1024]);
    *(int4*)(pw1 + (size_t)t * 8) = u.v;
}
// Stage2 frag (kk,im), lane(l15,qd): W2[e][hd = c*256+kk*32+qd*8+j][d = w*64+im*16+l15]
__global__ void pack_w2(const float* __restrict__ W2, unsigned short* __restrict__ pw2) {
    int t = blockIdx.x * 256 + threadIdx.x;
    int lane = t & 63;
    int l15 = lane & 15, qd = lane >> 4;
    int tt = (t >> 6) & 31;
    int im = tt & 3, kk = tt >> 2;
    int w = (t >> 11) & 3;
    int c = (t >> 13) & 3;
    int e = t >> 15;
    int hd0 = c * 256 + kk * 32 + qd * 8;
    int col = w * 64 + im * 16 + l15;
    const float* src = W2 + ((size_t)(e * 1024 + hd0)) * 256 + col;
    union { unsigned short s[8]; int4 v; } u;
#pragma unroll
    for (int j = 0; j < 8; ++j) u.s[j] = f2bf(src[(size_t)j * 256]);
    *(int4*)(pw2 + (size_t)t * 8) = u.v;
}

// ---------------- fused MoE block ----------------
__global__ __launch_bounds__(256, 2)
void moe_main(const float* __restrict__ H, const float* __restrict__ gate_w,
              const float* __restrict__ gate_b, const float* __restrict__ b1,
              const float* __restrict__ b2, const float* __restrict__ ln_g,
              const float* __restrict__ ln_b,
              const unsigned short* __restrict__ pw1,
              const unsigned short* __restrict__ pw2,
              float* __restrict__ out)
{
    __shared__ unsigned short sH[TN * LDH];     // 33792 B
    __shared__ unsigned short sHC[TN * LDH];    // 33792 B
    __shared__ float sGW[NE * GWS];             // 8320 B, [e][d] transposed
    __shared__ float sWts[NE * TN];             // 2048 B, [e][n]
    __shared__ float sRed[TN * 8];              // 2048 B
    __shared__ float sMu[TN * 2];               // 512 B   -> total 80512 B (2 blocks/CU)

    const int tid  = threadIdx.x;
    const int lane = tid & 63;
    const int wave = tid >> 6;
    const int l15  = lane & 15;
    const int quad = lane >> 4;
    const int node0 = blockIdx.x * TN;
    const int ncol  = wave * 64;     // this wave's hd-col (stage1) / d-col (stage2) base

    // ---- stage H tile (fp32 -> bf16 LDS, cvt_pk + b64 writes) + gate_w^T ----
    for (int i = tid; i < TN * (DD / 4); i += 256) {
        int row = i >> 6, c4 = i & 63;
        const float4 v = ((const float4*)(H + (size_t)(node0 + row) * DD))[c4];
        *(uint2*)&sH[row * LDH + c4 * 4] =
            make_uint2(cvt_pk_bf16(v.x, v.y), cvt_pk_bf16(v.z, v.w));
    }
    for (int i = tid; i < NE * DD; i += 256) {
        int e = i >> 8, d = i & 255;
        sGW[e * GWS + d] = gate_w[d * NE + e];
    }
    __syncthreads();

    // ---- prologue: prime the weight-fragment queue with s=0 stage1 t=0..15 ----
    bf16x8 q[4][4];
    {
        const unsigned short* p0 = pw1 + ((size_t)wave << 14) + lane * 8;
#pragma unroll
        for (int kk = 0; kk < 4; ++kk)
#pragma unroll
            for (int im = 0; im < 4; ++im)
                q[kk][im] = *(const bf16x8*)(p0 + (size_t)(kk * 4 + im) * 512);
    }

    // ---- gating (vectorized: b128 sH reads, float4 gate_w reads) ----
    for (int p = tid; p < TN * NE; p += 256) {
        int n = p >> 3, e = p & 7;
        const unsigned short* hr = &sH[n * LDH];
        const float* gr = &sGW[e * GWS];
        float a0 = gate_b[e], a1 = 0.f;
#pragma unroll 4
        for (int d8 = 0; d8 < 32; ++d8) {
            uint4 hv = *(const uint4*)(hr + d8 * 8);
            float4 g0 = *(const float4*)(gr + d8 * 8);
            float4 g1 = *(const float4*)(gr + d8 * 8 + 4);
            a0 = fmaf(__uint_as_float(hv.x << 16), g0.x, a0);
            a1 = fmaf(__uint_as_float(hv.x & 0xffff0000u), g0.y, a1);
            a0 = fmaf(__uint_as_float(hv.y << 16), g0.z, a0);
            a1 = fmaf(__uint_as_float(hv.y & 0xffff0000u), g0.w, a1);
            a0 = fmaf(__uint_as_float(hv.z << 16), g1.x, a0);
            a1 = fmaf(__uint_as_float(hv.z & 0xffff0000u), g1.y, a1);
            a0 = fmaf(__uint_as_float(hv.w << 16), g1.z, a0);
            a1 = fmaf(__uint_as_float(hv.w & 0xffff0000u), g1.w, a1);
        }
        sWts[e * TN + n] = a0 + a1;
    }
    __syncthreads();
    if (tid < TN) {
        float lg[8], mx = -1e30f;
#pragma unroll
        for (int e = 0; e < 8; ++e) { lg[e] = sWts[e * TN + tid]; mx = fmaxf(mx, lg[e]); }
        float ssum = 0.f;
#pragma unroll
        for (int e = 0; e < 8; ++e) { lg[e] = __expf(lg[e] - mx); ssum += lg[e]; }
        float inv = 1.0f / ssum;
#pragma unroll
        for (int e = 0; e < 8; ++e) sWts[e * TN + tid] = lg[e] * inv;
    }
    __syncthreads();

    // ---- main loop: 32 (e,c) iterations, rolling 4-batch weight prefetch ----
    const f32x4 ZV = {0.f, 0.f, 0.f, 0.f};
    f32x4 oacc[4][4];   // [im=d-tile][in=node-tile], D-layout: d=quad*4+r, node=l15
#pragma unroll
    for (int i = 0; i < 4; ++i)
#pragma unroll
        for (int j = 0; j < 4; ++j) oacc[i][j] = ZV;

#pragma unroll 1
    for (int s = 0; s < 32; ++s) {
        const int e = s >> 2, c = s & 3;
        const int sn = (s + 1) & 31;

        const unsigned short* p1  = pw1 + ((size_t)(s  * 4 + wave) << 14) + lane * 8;
        const unsigned short* p2  = pw2 + ((size_t)(s  * 4 + wave) << 14) + lane * 8;
        const unsigned short* p1n = pw1 + ((size_t)(sn * 4 + wave) << 14) + lane * 8;

        // ---- stage 1: acc1[hd][node] = W1chunk^T @ H^T ----
        f32x4 acc1[4][4];
#pragma unroll
        for (int kk = 0; kk < 8; ++kk) {
            const int slot = kk & 3;
            bf16x8 act[4], nq[4];
#pragma unroll
            for (int in = 0; in < 4; ++in)
                act[in] = *(const bf16x8*)&sH[(in * 16 + l15) * LDH + kk * 32 + quad * 8];
#pragma unroll
            for (int im = 0; im < 4; ++im)
                nq[im] = (kk < 4)
                    ? *(const bf16x8*)(p1 + (size_t)(16 + kk * 4 + im) * 512)
                    : *(const bf16x8*)(p2 + (size_t)((kk - 4) * 4 + im) * 512);
            __builtin_amdgcn_s_setprio(1);
#pragma unroll
            for (int im = 0; im < 4; ++im)
#pragma unroll
                for (int in = 0; in < 4; ++in)
                    acc1[im][in] = __builtin_amdgcn_mfma_f32_16x16x32_bf16(
                        q[slot][im], act[in], kk == 0 ? ZV : acc1[im][in], 0, 0, 0);
            __builtin_amdgcn_s_setprio(0);
#pragma unroll
            for (int im = 0; im < 4; ++im) q[slot][im] = nq[im];
        }

        float wge[4];
#pragma unroll
        for (int in = 0; in < 4; ++in) wge[in] = sWts[e * TN + in * 16 + l15];

        // ---- epilogue -> sHC (bf16 via cvt_pk), ds_write_b64 ----
#pragma unroll
        for (int im = 0; im < 4; ++im) {
            const float4 b1v = *(const float4*)&b1[e * HD + c * 256 + ncol + im * 16 + quad * 4];
#pragma unroll
            for (int in = 0; in < 4; ++in) {
                const float w = wge[in];
                float t0 = fmaxf(acc1[im][in][0] + b1v.x, 0.f) * w;
                float t1 = fmaxf(acc1[im][in][1] + b1v.y, 0.f) * w;
                float t2 = fmaxf(acc1[im][in][2] + b1v.z, 0.f) * w;
                float t3 = fmaxf(acc1[im][in][3] + b1v.w, 0.f) * w;
                *(uint2*)&sHC[(in * 16 + l15) * LDH + ncol + im * 16 + quad * 4] =
                    make_uint2(cvt_pk_bf16(t0, t1), cvt_pk_bf16(t2, t3));
            }
        }
        // raw barrier: drain only LDS writes; keep global prefetch queue in flight
        asm volatile("s_waitcnt lgkmcnt(0)" ::: "memory");
        __builtin_amdgcn_s_barrier();

        // ---- stage 2: oacc[d][node] += W2chunk^T @ hc^T ----
#pragma unroll
        for (int kk = 0; kk < 8; ++kk) {
            const int slot = kk & 3;
            bf16x8 act[4], nq[4];
#pragma unroll
            for (int in = 0; in < 4; ++in)
                act[in] = *(const bf16x8*)&sHC[(in * 16 + l15) * LDH + kk * 32 + quad * 8];
#pragma unroll
            for (int im = 0; im < 4; ++im)
                nq[im] = (kk < 4)
                    ? *(const bf16x8*)(p2 + (size_t)(16 + kk * 4 + im) * 512)
                    : *(const bf16x8*)(p1n + (size_t)((kk - 4) * 4 + im) * 512);
            __builtin_amdgcn_s_setprio(1);
#pragma unroll
            for (int im = 0; im < 4; ++im)
#pragma unroll
                for (int in = 0; in < 4; ++in)
                    oacc[im][in] = __builtin_amdgcn_mfma_f32_16x16x32_bf16(
                        q[slot][im], act[in], oacc[im][in], 0, 0, 0);
            __builtin_amdgcn_s_setprio(0);
#pragma unroll
            for (int im = 0; im < 4; ++im) q[slot][im] = nq[im];
        }
        // all sHC reads were consumed by MFMAs above -> bare barrier suffices
        __builtin_amdgcn_s_barrier();
    }

    // ---- epilogue: x = H + moe_out + sum_e w*b2 ; LayerNorm ----
    float wv[4][8];
#pragma unroll
    for (int in = 0; in < 4; ++in)
#pragma unroll
        for (int e2 = 0; e2 < 8; ++e2) wv[in][e2] = sWts[e2 * TN + in * 16 + l15];

    f32x4 wb2[4][4];    // [in][im]
#pragma unroll
    for (int in = 0; in < 4; ++in)
#pragma unroll
        for (int im = 0; im < 4; ++im) wb2[in][im] = (f32x4){0.f, 0.f, 0.f, 0.f};
#pragma unroll
    for (int e2 = 0; e2 < 8; ++e2)
#pragma unroll
        for (int im = 0; im < 4; ++im) {
            const float4 bv = *(const float4*)&b2[e2 * DD + ncol + im * 16 + quad * 4];
#pragma unroll
            for (int in = 0; in < 4; ++in) {
                wb2[in][im][0] = fmaf(wv[in][e2], bv.x, wb2[in][im][0]);
                wb2[in][im][1] = fmaf(wv[in][e2], bv.y, wb2[in][im][1]);
                wb2[in][im][2] = fmaf(wv[in][e2], bv.z, wb2[in][im][2]);
                wb2[in][im][3] = fmaf(wv[in][e2], bv.w, wb2[in][im][3]);
            }
        }

#pragma unroll
    for (int im = 0; im < 4; ++im)
#pragma unroll
        for (int in = 0; in < 4; ++in) {
            const float4 hres = *(const float4*)
                &H[(size_t)(node0 + in * 16 + l15) * DD + ncol + im * 16 + quad * 4];
            oacc[im][in][0] += hres.x + wb2[in][im][0];
            oacc[im][in][1] += hres.y + wb2[in][im][1];
            oacc[im][in][2] += hres.z + wb2[in][im][2];
            oacc[im][in][3] += hres.w + wb2[in][im][3];
        }

    // per-node sums: node = in*16+l15; reduce over quads (lane bits 4,5)
    float sum[4], sum2[4];
#pragma unroll
    for (int in = 0; in < 4; ++in) {
        float s = 0.f, s2 = 0.f;
#pragma unroll
        for (int im = 0; im < 4; ++im)
#pragma unroll
            for (int r = 0; r < 4; ++r) { float x = oacc[im][in][r]; s += x; s2 += x * x; }
        s  += __shfl_xor(s, 16);  s  += __shfl_xor(s, 32);
        s2 += __shfl_xor(s2, 16); s2 += __shfl_xor(s2, 32);
        sum[in] = s; sum2[in] = s2;
    }
    if (quad == 0) {
#pragma unroll
        for (int in = 0; in < 4; ++in) {
            sRed[(in * 16 + l15) * 8 + wave * 2]     = sum[in];
            sRed[(in * 16 + l15) * 8 + wave * 2 + 1] = sum2[in];
        }
    }
    __syncthreads();
    if (tid < TN) {
        float s = 0.f, s2 = 0.f;
#pragma unroll
        for (int w2 = 0; w2 < 4; ++w2) { s += sRed[tid * 8 + w2 * 2]; s2 += sRed[tid * 8 + w2 * 2 + 1]; }
        float mu  = s * (1.0f / 256.0f);
        float var = s2 * (1.0f / 256.0f) - mu * mu;
        sMu[tid * 2] = mu;
        sMu[tid * 2 + 1] = rsqrtf(var + LN_EPS);
    }
    __syncthreads();

#pragma unroll
    for (int im = 0; im < 4; ++im) {
        const float4 lgv = *(const float4*)&ln_g[ncol + im * 16 + quad * 4];
        const float4 lbv = *(const float4*)&ln_b[ncol + im * 16 + quad * 4];
#pragma unroll
        for (int in = 0; in < 4; ++in) {
            const int node = in * 16 + l15;
            const float mu = sMu[node * 2], rs = sMu[node * 2 + 1];
            float4 y;
            y.x = (oacc[im][in][0] - mu) * rs * lgv.x + lbv.x;
            y.y = (oacc[im][in][1] - mu) * rs * lgv.y + lbv.y;
            y.z = (oacc[im][in][2] - mu) * rs * lgv.z + lbv.z;
            y.w = (oacc[im][in][3] - mu) * rs * lgv.w + lbv.w;
            *(float4*)&out[(size_t)(node0 + node) * DD + ncol + im * 16 + quad * 4] = y;
        }
    }
}

extern "C" void kernel_launch(void* const* d_in, const int* in_sizes, int n_in,
                              void* d_out, int out_size, void* d_ws, size_t ws_size,
                              hipStream_t stream) {
    const float* H   = (const float*)d_in[0];
    const float* gw  = (const float*)d_in[1];
    const float* gb  = (const float*)d_in[2];
    const float* W1  = (const float*)d_in[3];
    const float* b1  = (const float*)d_in[4];
    const float* W2  = (const float*)d_in[5];
    const float* b2  = (const float*)d_in[6];
    const float* lng = (const float*)d_in[7];
    const float* lnb = (const float*)d_in[8];
    float* out = (float*)d_out;

    unsigned short* pw1 = (unsigned short*)d_ws;                 // 4 MB
    unsigned short* pw2 = pw1 + (size_t)8 * 32 * 1024 * 8;       // 4 MB

    hipLaunchKernelGGL(pack_w1, dim3(1024), dim3(256), 0, stream, W1, pw1);
    hipLaunchKernelGGL(pack_w2, dim3(1024), dim3(256), 0, stream, W2, pw2);
    hipLaunchKernelGGL(moe_main, dim3(65536 / TN), dim3(256), 0, stream,
                       H, gw, gb, b1, b2, lng, lnb, pw1, pw2, out);
}